// Round 4
// baseline (548.999 us; speedup 1.0000x reference)
//
#include <hip/hip_runtime.h>
#include <hip/hip_bf16.h>

#define B_ 32
#define C_ 512
#define N_ 4096
#define T_ 72
#define K_ 64
#define KP 80            // clusters padded to 5 MFMA m-tiles
#define EPSF 1e-12f

typedef unsigned short u16;
typedef unsigned int u32;
typedef __attribute__((ext_vector_type(8))) short bf16x8;
typedef __attribute__((ext_vector_type(4))) float f32x4;

__device__ __forceinline__ u16 f2bf(float v) {
    __hip_bfloat16 h = __float2bfloat16(v);   // RNE
    return *reinterpret_cast<u16*>(&h);
}
__device__ __forceinline__ u32 pk_bf16(float a, float b) {
    union { __hip_bfloat162 h; u32 u; } cvt;
    cvt.h = __float22bfloat162_rn(make_float2(a, b));
    return cvt.u;
}

// ---------------------------------------------------------------------------
// Prep: W padded [80][512] bf16 (rows >=72 zero); bias padded with -1e30.
// ---------------------------------------------------------------------------
__global__ __launch_bounds__(256) void k_prep(
    const float* __restrict__ conv_w, const float* __restrict__ conv_b,
    u16* __restrict__ Wp, float* __restrict__ bp)
{
    const int idx = blockIdx.x * 256 + threadIdx.x;
    if (idx < KP * C_) {
        const int k = idx >> 9, c = idx & (C_ - 1);
        Wp[idx] = f2bf(k < T_ ? conv_w[k * C_ + c] : 0.f);
    } else if (idx < KP * C_ + KP) {
        const int j = idx - KP * C_;
        bp[j] = (j < T_) ? conv_b[j] : -1e30f;
    }
}

// ---------------------------------------------------------------------------
// Assign: 64 n per block. Staging loads are float4 ALONG n (contiguous,
// independent -> deep pipelining); fp32 sumsq via per-n-quad LDS reduce;
// bf16 transpose-scatter into an XOR-swizzled unpadded LDS tile
// (U = (c>>3) ^ (n>>3): write banks fully spread, b128 frag reads at floor).
// MFMA 16x16x32 over 5 m-tiles (80 clusters); softmax in C-layout registers;
// stores a' = a*inv_norm (bf16) + mass atomics.  LDS ~37 KB -> 4 blocks/CU.
// ---------------------------------------------------------------------------
__global__ __launch_bounds__(256) void k_assign(
    const float* __restrict__ x, const u16* __restrict__ Wp,
    const float* __restrict__ bp, u16* __restrict__ assignp,
    float* __restrict__ mass)
{
    __shared__ u16   xt[64 * 256];     // swizzled [n][c-chunk]
    __shared__ f32x4 red[16][16];      // [rowgrp][nquad]
    __shared__ float linv[64];

    const int t  = threadIdx.x;
    const int b  = blockIdx.y;
    const int n0 = blockIdx.x * 64;

    const int lane = t & 63, w = t >> 6;
    const int q = lane >> 4, nl = lane & 15;

    // staging ownership: thread owns n-quad nq (4 n), c-rows rg+16p
    const int nq  = t & 15;
    const int rg  = t >> 4;
    const int nlo = 4 * nq;
    const int nsh = nq >> 1;           // == (nlo+j)>>3 for j in 0..3

    f32x4 ss = {0.f, 0.f, 0.f, 0.f};
    f32x4 acc[5];
    #pragma unroll
    for (int mt = 0; mt < 5; ++mt) acc[mt] = (f32x4)0.f;

    #pragma unroll 1
    for (int half = 0; half < 2; ++half) {
        const int cbase = half * 256;
        __syncthreads();               // xt safe to overwrite
        // ---- stage [64n][256c]: 16 float4 loads along n per thread ----
        #pragma unroll 8
        for (int p = 0; p < 16; ++p) {
            const int cr = rg + 16 * p;
            const float4 v = *(const float4*)(
                x + ((size_t)b * C_ + cbase + cr) * N_ + n0 + nlo);
            ss.x = fmaf(v.x, v.x, ss.x);
            ss.y = fmaf(v.y, v.y, ss.y);
            ss.z = fmaf(v.z, v.z, ss.z);
            ss.w = fmaf(v.w, v.w, ss.w);
            const u32 p01 = pk_bf16(v.x, v.y);
            const u32 p23 = pk_bf16(v.z, v.w);
            const int uoff = ((((cr >> 3) ^ nsh) << 3)) + (cr & 7);
            xt[(nlo + 0) * 256 + uoff] = (u16)(p01 & 0xffff);
            xt[(nlo + 1) * 256 + uoff] = (u16)(p01 >> 16);
            xt[(nlo + 2) * 256 + uoff] = (u16)(p23 & 0xffff);
            xt[(nlo + 3) * 256 + uoff] = (u16)(p23 >> 16);
        }
        __syncthreads();
        // ---- MFMA K-loop (A = W from global/L2, B = xt swizzled) ----
        const u16* wrow = Wp + (size_t)nl * C_ + cbase + q * 8;
        const int nrow = 16 * w + nl;
        const int nrs  = nrow >> 3;
        #pragma unroll
        for (int ks = 0; ks < 8; ++ks) {
            const bf16x8 bfr = *(const bf16x8*)(
                &xt[nrow * 256 + (((ks * 4 + q) ^ nrs) << 3)]);
            #pragma unroll
            for (int mt = 0; mt < 5; ++mt) {
                const bf16x8 af = *(const bf16x8*)(
                    wrow + (size_t)(mt * 16) * C_ + ks * 32);
                acc[mt] = __builtin_amdgcn_mfma_f32_16x16x32_bf16(af, bfr, acc[mt], 0, 0, 0);
            }
        }
    }

    // ---- per-n inv_norm: reduce ss over the 16 row-groups ----
    red[rg][nq] = ss;
    __syncthreads();
    if (t < 64) {
        float s = 0.f;
        #pragma unroll
        for (int g = 0; g < 16; ++g) s += red[g][t >> 2][t & 3];
        linv[t] = 1.0f / fmaxf(sqrtf(s), EPSF);
    }
    __syncthreads();

    // ---- epilogue (validated round 3): softmax over 80 (pads -> 0) ----
    const float invn  = linv[16 * w + nl];
    const int   nglob = n0 + 16 * w + nl;

    float lg[5][4];
    #pragma unroll
    for (int mt = 0; mt < 5; ++mt)
        #pragma unroll
        for (int r = 0; r < 4; ++r)
            lg[mt][r] = acc[mt][r] * invn + bp[mt * 16 + q * 4 + r];

    float mx = -1e30f;
    #pragma unroll
    for (int mt = 0; mt < 5; ++mt)
        #pragma unroll
        for (int r = 0; r < 4; ++r) mx = fmaxf(mx, lg[mt][r]);
    mx = fmaxf(mx, __shfl_xor(mx, 16, 64));
    mx = fmaxf(mx, __shfl_xor(mx, 32, 64));

    float s = 0.f;
    #pragma unroll
    for (int mt = 0; mt < 5; ++mt)
        #pragma unroll
        for (int r = 0; r < 4; ++r) {
            lg[mt][r] = __expf(lg[mt][r] - mx);
            s += lg[mt][r];
        }
    s += __shfl_xor(s, 16, 64);
    s += __shfl_xor(s, 32, 64);
    const float rs = 1.0f / s;

    #pragma unroll
    for (int mt = 0; mt < 4; ++mt)          // real clusters only
        #pragma unroll
        for (int r = 0; r < 4; ++r) {
            const float a = lg[mt][r] * rs;
            float msum = a;
            msum += __shfl_xor(msum, 1, 64);
            msum += __shfl_xor(msum, 2, 64);
            msum += __shfl_xor(msum, 4, 64);
            msum += __shfl_xor(msum, 8, 64);
            const int k = mt * 16 + q * 4 + r;
            if (nl == 0) atomicAdd(&mass[b * K_ + k], msum);
            assignp[((size_t)b * K_ + k) * N_ + nglob] = f2bf(a * invn);
        }
}

// ---------------------------------------------------------------------------
// Agg: part[j][b][k][c] = sum_{n in chunk j} a'[k,n]*x_bf16[c,n].
// 64k x 128c tile, K = 1024 n per block (16 rounds of 64). A staged as
// direct bf16 b128; B from fp32 x with packed cvt, b128 writes. Same XOR
// swizzle. NO atomics: 4 partials reduced in k_rnorm. LDS 24 KB.
// ---------------------------------------------------------------------------
#define AW 128
#define ANC 4
__global__ __launch_bounds__(256) void k_agg(
    const float* __restrict__ x, const u16* __restrict__ assignp,
    float* __restrict__ part)
{
    __shared__ u16 Aa[64 * 64];
    __shared__ u16 Bb[AW * 64];

    const int t  = threadIdx.x;
    const int b  = blockIdx.z;
    const int j  = blockIdx.y;
    const int c0 = blockIdx.x * AW;

    const int lane = t & 63, w = t >> 6;
    const int q = lane >> 4, nl = lane & 15;

    f32x4 acc[4][2];
    #pragma unroll
    for (int mt = 0; mt < 4; ++mt)
        #pragma unroll
        for (int ct = 0; ct < 2; ++ct) acc[mt][ct] = (f32x4)0.f;

    const u16*   ab = assignp + (size_t)b * K_ * N_;
    const float* xb = x + ((size_t)b * C_ + c0) * N_;

    const int su = t & 7;       // 8-n unit
    const int sr = t >> 3;      // row base 0..31

    #pragma unroll 1
    for (int n0 = j * (N_ / ANC); n0 < (j + 1) * (N_ / ANC); n0 += 64) {
        __syncthreads();
        // A: 64 rows (k) x 64 n, direct bf16
        #pragma unroll
        for (int p = 0; p < 2; ++p) {
            const int k = sr + 32 * p;
            const uint4 av = *(const uint4*)(ab + (size_t)k * N_ + n0 + su * 8);
            *(uint4*)(&Aa[k * 64 + ((su ^ ((k >> 3) & 7)) << 3)]) = av;
        }
        // B: 128 rows (c) x 64 n, fp32 -> bf16 packed
        #pragma unroll
        for (int p = 0; p < 4; ++p) {
            const int c = sr + 32 * p;
            const float4 v0 = *(const float4*)(xb + (size_t)c * N_ + n0 + su * 8);
            const float4 v1 = *(const float4*)(xb + (size_t)c * N_ + n0 + su * 8 + 4);
            uint4 pk;
            pk.x = pk_bf16(v0.x, v0.y); pk.y = pk_bf16(v0.z, v0.w);
            pk.z = pk_bf16(v1.x, v1.y); pk.w = pk_bf16(v1.z, v1.w);
            *(uint4*)(&Bb[c * 64 + ((su ^ ((c >> 3) & 7)) << 3)]) = pk;
        }
        __syncthreads();
        #pragma unroll
        for (int kk = 0; kk < 2; ++kk) {
            bf16x8 bfr[2];
            #pragma unroll
            for (int ct = 0; ct < 2; ++ct) {
                const int crow = 32 * w + ct * 16 + nl;
                bfr[ct] = *(const bf16x8*)(
                    &Bb[crow * 64 + (((kk * 4 + q) ^ ((crow >> 3) & 7)) << 3)]);
            }
            #pragma unroll
            for (int mt = 0; mt < 4; ++mt) {
                const int krow = mt * 16 + nl;
                const bf16x8 af = *(const bf16x8*)(
                    &Aa[krow * 64 + (((kk * 4 + q) ^ ((krow >> 3) & 7)) << 3)]);
                acc[mt][0] = __builtin_amdgcn_mfma_f32_16x16x32_bf16(af, bfr[0], acc[mt][0], 0, 0, 0);
                acc[mt][1] = __builtin_amdgcn_mfma_f32_16x16x32_bf16(af, bfr[1], acc[mt][1], 0, 0, 0);
            }
        }
    }

    float* pb = part + (((size_t)j * B_ + b) * K_) * C_;
    #pragma unroll
    for (int mt = 0; mt < 4; ++mt)
        #pragma unroll
        for (int ct = 0; ct < 2; ++ct)
            #pragma unroll
            for (int r = 0; r < 4; ++r) {
                const int k = mt * 16 + q * 4 + r;
                const int c = c0 + 32 * w + ct * 16 + nl;
                pb[(size_t)k * C_ + c] = acc[mt][ct][r];
            }
}

// ---------------------------------------------------------------------------
// Reduce partials + centroid*mass -> vlad (to out) + row norms + global norm.
// ---------------------------------------------------------------------------
__device__ __forceinline__ float block_reduce_sum_256(float v) {
    #pragma unroll
    for (int o = 32; o > 0; o >>= 1) v += __shfl_down(v, o, 64);
    __shared__ float wsh[4];
    const int lane = threadIdx.x & 63, wid = threadIdx.x >> 6;
    if (lane == 0) wsh[wid] = v;
    __syncthreads();
    float r = 0.f;
    if (threadIdx.x == 0) r = wsh[0] + wsh[1] + wsh[2] + wsh[3];
    return r;
}

__global__ __launch_bounds__(256) void k_rnorm(
    const float* __restrict__ part, const float* __restrict__ centroids,
    const float* __restrict__ mass, float* __restrict__ out,
    float* __restrict__ rnorm, float* __restrict__ gsum)
{
    const int k = blockIdx.x, b = blockIdx.y;
    const float mk = mass[b * K_ + k];
    const size_t rowoff = ((size_t)b * K_ + k) * C_;
    const size_t pstride = (size_t)B_ * K_ * C_;
    float s = 0.f;
    #pragma unroll
    for (int i = threadIdx.x; i < C_; i += 256) {
        float v = -centroids[k * C_ + i] * mk;
        #pragma unroll
        for (int jj = 0; jj < ANC; ++jj) v += part[jj * pstride + rowoff + i];
        out[rowoff + i] = v;
        s = fmaf(v, v, s);
    }
    const float ss = block_reduce_sum_256(s);
    if (threadIdx.x == 0) {
        const float rn = fmaxf(sqrtf(ss), EPSF);
        rnorm[b * K_ + k] = rn;
        atomicAdd(gsum + b, ss / (rn * rn));
    }
}

__global__ __launch_bounds__(256) void k_final(
    float* __restrict__ out, const float* __restrict__ rnorm,
    const float* __restrict__ gsum)
{
    const size_t i4 = ((size_t)blockIdx.x * 256 + threadIdx.x) * 4;
    const int b = (int)(i4 >> 15);
    const int k = (int)((i4 >> 9) & 63);
    const float gn = fmaxf(sqrtf(gsum[b]), EPSF);
    const float sc = 1.0f / (rnorm[b * K_ + k] * gn);
    float4 v = *(const float4*)(out + i4);
    v.x *= sc; v.y *= sc; v.z *= sc; v.w *= sc;
    *(float4*)(out + i4) = v;
}

// ---------------------------------------------------------------------------
extern "C" void kernel_launch(void* const* d_in, const int* in_sizes, int n_in,
                              void* d_out, int out_size, void* d_ws, size_t ws_size,
                              hipStream_t stream) {
    const float* x         = (const float*)d_in[0];
    const float* centroids = (const float*)d_in[1];
    const float* conv_w    = (const float*)d_in[2];
    const float* conv_b    = (const float*)d_in[3];
    // d_in[4..8] (ghost_weights, w1, b1, w2, b2): positive per-row scalars
    // cancel inside the intra-cluster L2 norm; ghost rows dropped -> unused.

    float* out = (float*)d_out;
    char*  ws  = (char*)d_ws;

    u16*   assignp = (u16*)ws;                            // 16 MB
    float* part    = (float*)(ws + (16u << 20));          // 32 MB (ANC=4)
    char*  tail    = ws + (48u << 20);
    u16*   Wp      = (u16*)tail;                          // 80 KB
    float* bpad    = (float*)(tail + 81920);              // 320 B
    float* mass    = (float*)(tail + 81920 + 320);        // 8 KB
    float* rnorm   = mass + B_ * K_;                      // 8 KB
    float* gsum    = rnorm + B_ * K_;                     // 128 B

    hipMemsetAsync(mass, 0, B_ * K_ * sizeof(float), stream);
    hipMemsetAsync(gsum, 0, B_ * sizeof(float), stream);

    k_prep<<<dim3((KP * C_ + KP + 255) / 256), 256, 0, stream>>>(conv_w, conv_b, Wp, bpad);
    k_assign<<<dim3(N_ / 64, B_), 256, 0, stream>>>(x, Wp, bpad, assignp, mass);
    k_agg<<<dim3(C_ / AW, ANC, B_), 256, 0, stream>>>(x, assignp, part);
    k_rnorm<<<dim3(K_, B_), 256, 0, stream>>>(part, centroids, mass, out, rnorm, gsum);
    k_final<<<(out_size / 4 + 255) / 256, 256, 0, stream>>>(out, rnorm, gsum);
}